// Round 7
// baseline (450.324 us; speedup 1.0000x reference)
//
#include <hip/hip_runtime.h>
#include <hip/hip_bf16.h>

#define BDIM 1024
#define VDIM 6890
#define NJ   24
#define NCOL (VDIM*3)   // 20670
#define KPAD 224        // 207 padded to 7*32
#define NPAD 20736      // 81*256 columns for GEMM guardless loads

// fp32-element offsets into d_out (float*):
#define OUT_VERTS   0
#define OUT_JPOSED  21166080
#define OUT_JREST   21239808
#define OUT_A       21313536
#define OUT_VSHAPED 21706752

// Scratch inside the verts region of d_out (dead before k_lbs writes verts).
// Offsets in fp32 elements; pdt/pf are bf16 arrays living in that space.
#define SCRF_PDT    0          // bf16 NPAD*KPAD = 4,644,864 el -> 2,322,432 f32 slots
#define SCRF_PF     2322432    // bf16 1024*224  =   229,376 el ->   114,688 f32 slots
#define SCRF_JTJS   2437120    // 792 f32

typedef __hip_bfloat16 bf16;
typedef unsigned short ushort_t;
typedef __attribute__((ext_vector_type(8))) short  short8;
typedef __attribute__((ext_vector_type(4))) float  float4v;

__device__ __forceinline__ bf16  tob(float x) { return __float2bfloat16(x); }

// ---------------- Kernel A: JT/JS precompute (batch-independent) ----------------
__global__ __launch_bounds__(256) void k_jtjs(const float* __restrict__ jreg,
        const float* __restrict__ vt, const float* __restrict__ sd,
        float* __restrict__ jtjs) {
    int j = blockIdx.x;
    int tid = threadIdx.x;
    float acc[33];
#pragma unroll
    for (int i = 0; i < 33; i++) acc[i] = 0.f;
    for (int v = tid; v < VDIM; v += 256) {
        float r = jreg[j*VDIM + v];
#pragma unroll
        for (int m = 0; m < 3; m++) {
            acc[m] += r * vt[v*3+m];
#pragma unroll
            for (int l = 0; l < 10; l++)
                acc[3 + m*10 + l] += r * sd[(v*3+m)*10 + l];
        }
    }
    __shared__ float red[4][33];
    int lane = tid & 63, wid = tid >> 6;
#pragma unroll
    for (int i = 0; i < 33; i++) {
        float x = acc[i];
        for (int off = 32; off > 0; off >>= 1) x += __shfl_down(x, off);
        if (lane == 0) red[wid][i] = x;
    }
    __syncthreads();
    if (tid < 33)
        jtjs[j*33 + tid] = red[0][tid] + red[1][tid] + red[2][tid] + red[3][tid];
}

// ---------------- Kernel PT: transpose posedirs f32 (207 x 20670) -> bf16 (NPAD x 224) ----------------
__global__ __launch_bounds__(256) void k_transpose(const float* __restrict__ pd,
        bf16* __restrict__ pdt) {
    __shared__ bf16 tile[32][65];
    int nt = blockIdx.x * 64;
    int kt = blockIdx.y * 32;
    int t = threadIdx.x;
    for (int i = t; i < 32*64; i += 256) {
        int kk = i >> 6, nn = i & 63;
        int k = kt + kk, n = nt + nn;
        float v = 0.f;
        if (k < 207 && n < NCOL) v = pd[k*NCOL + n];
        tile[kk][nn] = tob(v);
    }
    __syncthreads();
    for (int i = t; i < 32*64; i += 256) {
        int kk = i & 31, nn = i >> 5;
        pdt[(nt + nn)*KPAD + kt + kk] = tile[kk][nn];
    }
}

// ---------------- Kernel B: per-batch pose (Rodrigues, chain, A, J_rest, J_posed) ----------------
__global__ __launch_bounds__(64) void k_pose(const float* __restrict__ betas,
        const float* __restrict__ pose, const int* __restrict__ parents,
        const float* __restrict__ jtjs, float* __restrict__ out,
        bf16* __restrict__ wspf) {
    int b = blockIdx.x, t = threadIdx.x;
    __shared__ float R[24][9];
    __shared__ float jrest[24][3];
    __shared__ float rel[24][3];
    __shared__ float ch[24][12];
    __shared__ int par[24];
    if (t < 24) {
        par[t] = parents[t];
        float rx = pose[b*72 + t*3 + 0];
        float ry = pose[b*72 + t*3 + 1];
        float rz = pose[b*72 + t*3 + 2];
        float ax = rx + 1e-8f, ay = ry + 1e-8f, az = rz + 1e-8f;
        float angle = sqrtf(ax*ax + ay*ay + az*az);
        float inv = 1.0f / angle;               // axis = original r / angle (ref semantics)
        float kx = rx*inv, ky = ry*inv, kz = rz*inv;
        float s = sinf(angle), c = cosf(angle);
        float t1 = 1.0f - c;
        float q = kx*kx + ky*ky + kz*kz;        // K^2 = kk^T - (k.k) I
        R[t][0] = 1.f + t1*(kx*kx - q);
        R[t][1] = -s*kz + t1*kx*ky;
        R[t][2] =  s*ky + t1*kx*kz;
        R[t][3] =  s*kz + t1*kx*ky;
        R[t][4] = 1.f + t1*(ky*ky - q);
        R[t][5] = -s*kx + t1*ky*kz;
        R[t][6] = -s*ky + t1*kx*kz;
        R[t][7] =  s*kx + t1*ky*kz;
        R[t][8] = 1.f + t1*(kz*kz - q);
    }
    __syncthreads();
    // pose_feature -> scratch (bf16, zero-padded to KPAD)
    for (int i = t; i < KPAD; i += 64) {
        float pf = 0.f;
        if (i < 207) {
            int j = i/9 + 1, e = i - (j-1)*9;
            pf = R[j][e] - ((e == 0 || e == 4 || e == 8) ? 1.f : 0.f);
        }
        wspf[b*KPAD + i] = tob(pf);
    }
    // J_rest = JT + JS . betas   (64 threads -> strided loop over 72)
    for (int i = t; i < 72; i += 64) {
        int j = i/3, k = i - j*3;
        const float* JJ = &jtjs[j*33];
        float s = JJ[k];
#pragma unroll
        for (int l = 0; l < 10; l++) s += JJ[3 + k*10 + l] * betas[b*10 + l];
        jrest[j][k] = s;
        out[OUT_JREST + b*72 + i] = s;
    }
    __syncthreads();
    for (int i = t; i < 72; i += 64) {
        int j = i/3, k = i - j*3;
        rel[j][k] = jrest[j][k] - (j > 0 ? jrest[par[j]][k] : 0.f);
    }
    __syncthreads();
    if (t < 12) {
        int m = t >> 2, n = t & 3;
        ch[0][t] = (n < 3) ? R[0][m*3+n] : rel[0][m];
    }
    __syncthreads();
    for (int i = 1; i < 24; i++) {
        float val = 0.f;
        if (t < 12) {
            int m = t >> 2, n = t & 3;
            int p = par[i];                      // p < i: no overlap with ch[i] write
            if (n < 3)
                val = ch[p][m*4+0]*R[i][n] + ch[p][m*4+1]*R[i][3+n] + ch[p][m*4+2]*R[i][6+n];
            else
                val = ch[p][m*4+0]*rel[i][0] + ch[p][m*4+1]*rel[i][1]
                    + ch[p][m*4+2]*rel[i][2] + ch[p][m*4+3];
        }
        if (t < 12) ch[i][t] = val;
        __syncthreads();
    }
    for (int i = t; i < 72; i += 64) {
        int j = i/3, k = i - j*3;
        out[OUT_JPOSED + b*72 + i] = ch[j][k*4+3];
    }
    // A = chain with translation t - R*jrest (fp32 output; k_lbs re-reads it)
    for (int i = t; i < 384; i += 64) {
        int j = i >> 4, e = i & 15, m = e >> 2, n = e & 3;
        float v;
        if (m < 3) {
            if (n < 3) v = ch[j][m*4+n];
            else v = ch[j][m*4+3] - (ch[j][m*4+0]*jrest[j][0] + ch[j][m*4+1]*jrest[j][1]
                                   + ch[j][m*4+2]*jrest[j][2]);
        } else v = (n == 3) ? 1.f : 0.f;
        out[OUT_A + b*384 + i] = v;
    }
}

// ---------------- Kernel D: pose GEMM via MFMA: delta = pf (B x 224) @ posedirs (224 x 20670) ----------------
__global__ __launch_bounds__(256) void k_posegemm(const bf16* __restrict__ wspf,
        const bf16* __restrict__ wspdt, float* __restrict__ dout) {
    const ushort_t* pf  = (const ushort_t*)wspf;
    const ushort_t* pdt = (const ushort_t*)wspdt;
    int lane = threadIdx.x & 63;
    int wave = threadIdx.x >> 6;
    int l15 = lane & 15, quad = lane >> 4;
    int m0 = blockIdx.y * 32;
    int n0 = blockIdx.x * 256 + wave * 64;
    float4v acc[2][4] = {};
    for (int c = 0; c < 7; c++) {
        short8 a[2], bb[4];
#pragma unroll
        for (int mf = 0; mf < 2; mf++)
            a[mf] = *reinterpret_cast<const short8*>(pf + (m0 + mf*16 + l15)*KPAD + c*32 + quad*8);
#pragma unroll
        for (int nf = 0; nf < 4; nf++)
            bb[nf] = *reinterpret_cast<const short8*>(pdt + (n0 + nf*16 + l15)*KPAD + c*32 + quad*8);
#pragma unroll
        for (int mf = 0; mf < 2; mf++)
#pragma unroll
            for (int nf = 0; nf < 4; nf++)
                acc[mf][nf] = __builtin_amdgcn_mfma_f32_16x16x32_bf16(a[mf], bb[nf], acc[mf][nf], 0, 0, 0);
    }
#pragma unroll
    for (int mf = 0; mf < 2; mf++)
#pragma unroll
        for (int nf = 0; nf < 4; nf++) {
            int col = n0 + nf*16 + l15;
            if (col < NCOL) {
#pragma unroll
                for (int r = 0; r < 4; r++) {
                    int row = m0 + mf*16 + quad*4 + r;   // C/D: col=lane&15, row=quad*4+reg
                    dout[row*NCOL + col] = acc[mf][nf][r];
                }
            }
        }
}

// ---------------- Kernel E: v_shaped + LBS + verts ----------------
// Reads pose-delta (fp32) from the v_shaped out region (scratch) and A (fp32);
// overwrites scratch with true v_shaped, writes verts.
__global__ __launch_bounds__(256) void k_lbs(const float* __restrict__ betas,
        const float* __restrict__ sd, const float* __restrict__ vt,
        const float* __restrict__ lbs, float* __restrict__ out) {
    __shared__ __align__(16) float Ash[288];
    int tid = threadIdx.x;
    int b = blockIdx.y;
    for (int i = tid; i < 288; i += 256) {
        int j = i / 12, r = i - j*12;            // A layout: b*384 + j*16 + (m*4+n), m<3
        Ash[i] = out[OUT_A + b*384 + j*16 + r];
    }
    __syncthreads();
    int v = blockIdx.x*256 + tid;
    if (v >= VDIM) return;
    float bbv[10];
#pragma unroll
    for (int l = 0; l < 10; l++) bbv[l] = betas[b*10 + l];
    float vs[3];
#pragma unroll
    for (int m = 0; m < 3; m++) {
        float s = vt[v*3 + m];
#pragma unroll
        for (int l = 0; l < 10; l++) s += bbv[l] * sd[(v*3+m)*10 + l];
        vs[m] = s;
    }
    float* vsh = out + OUT_VSHAPED;
    int base = b*NCOL + v*3;
    float vp[3];
#pragma unroll
    for (int m = 0; m < 3; m++) vp[m] = vs[m] + vsh[base + m];
    float T[12];
#pragma unroll
    for (int e = 0; e < 12; e++) T[e] = 0.f;
    for (int j = 0; j < 24; j++) {
        float w = lbs[v*24 + j];
        const float4* A4 = reinterpret_cast<const float4*>(&Ash[j*12]);
        float4 a0 = A4[0], a1 = A4[1], a2 = A4[2];
        T[0] += w*a0.x; T[1] += w*a0.y; T[2]  += w*a0.z; T[3]  += w*a0.w;
        T[4] += w*a1.x; T[5] += w*a1.y; T[6]  += w*a1.z; T[7]  += w*a1.w;
        T[8] += w*a2.x; T[9] += w*a2.y; T[10] += w*a2.z; T[11] += w*a2.w;
    }
#pragma unroll
    for (int m = 0; m < 3; m++) {
        float o = T[m*4+3] + T[m*4]*vp[0] + T[m*4+1]*vp[1] + T[m*4+2]*vp[2];
        out[base + m] = o;             // verts at offset 0
        vsh[base + m] = vs[m];         // overwrite scratch with v_shaped
    }
}

extern "C" void kernel_launch(void* const* d_in, const int* in_sizes, int n_in,
                              void* d_out, int out_size, void* d_ws, size_t ws_size,
                              hipStream_t stream) {
    // Bind inputs BY SIZE (robust to dict-order vs alphabetical flattening;
    // the 165360 pair J_regressor/lbs_weights keeps relative order in both).
    const float *betas = nullptr, *pose = nullptr, *vt = nullptr, *sd = nullptr,
                *pd = nullptr, *jreg = nullptr, *lbs = nullptr;
    const int* parents = nullptr;
    for (int i = 0; i < n_in; i++) {
        switch (in_sizes[i]) {
            case 10240:   betas = (const float*)d_in[i]; break;      // (1024,10)
            case 73728:   pose  = (const float*)d_in[i]; break;      // (1024,72)
            case 20670:   vt    = (const float*)d_in[i]; break;      // (1,6890,3)
            case 206700:  sd    = (const float*)d_in[i]; break;      // (6890,3,10)
            case 4278690: pd    = (const float*)d_in[i]; break;      // (207,20670)
            case 24:      parents = (const int*)d_in[i]; break;      // (24,)
            case 165360:                                             // (24,6890)/(6890,24)
                if (!jreg) jreg = (const float*)d_in[i];
                else       lbs  = (const float*)d_in[i];
                break;
            default: break;
        }
    }
    float* out = (float*)d_out;   // reference output dtype is float32
    (void)d_ws; (void)ws_size;

    // Scratch in the verts region of d_out (dead before k_lbs writes verts):
    bf16*  ws_pdt  = (bf16*)(out + SCRF_PDT);
    bf16*  ws_pf   = (bf16*)(out + SCRF_PF);
    float* ws_jtjs = out + SCRF_JTJS;

    k_jtjs<<<24, 256, 0, stream>>>(jreg, vt, sd, ws_jtjs);
    k_transpose<<<dim3(324, 7), 256, 0, stream>>>(pd, ws_pdt);
    k_pose<<<BDIM, 64, 0, stream>>>(betas, pose, parents, ws_jtjs, out, ws_pf);
    k_posegemm<<<dim3(81, 32), 256, 0, stream>>>(ws_pf, ws_pdt, out + OUT_VSHAPED);
    k_lbs<<<dim3(27, BDIM), 256, 0, stream>>>(betas, sd, vt, lbs, out);
}